// Round 1
// baseline (321.955 us; speedup 1.0000x reference)
//
#include <hip/hip_runtime.h>
#include <stdint.h>

typedef unsigned short u16;
typedef short bf16x8 __attribute__((ext_vector_type(8)));   // 8 bf16 in 4 VGPRs
typedef float f32x4 __attribute__((ext_vector_type(4)));

typedef void as1_void __attribute__((address_space(1)));
typedef void as3_void __attribute__((address_space(3)));

__device__ inline u16 f32_to_bf16(float f) {
    uint32_t u = __builtin_bit_cast(uint32_t, f);
    u += 0x7fffu + ((u >> 16) & 1u);   // RNE (finite values only)
    return (u16)(u >> 16);
}

__device__ inline void gld_lds16(const void* g, void* l) {
    // async global->LDS, 16B/lane; HW dest = wave-uniform base + lane*16
    __builtin_amdgcn_global_load_lds((as1_void*)g, (as3_void*)l, 16, 0, 0);
}

// LDS tile layout (both GEMMs): 128 rows x 64 cols bf16, stored as 1024 chunks of
// 16B. Global (row, colchunk j) lives at chunk slot row*8 + (j ^ (row&7)).
// The XOR swizzle spreads same-column frag reads across all 32 banks (2-way max,
// free per m136) while keeping each staging issue 64 lane-contiguous slots.

// ---------------- merged prep kernel ----------------
// blocks [0,4096):     Ccat[o][k] = [Cr | -Ci]  row-major [1024][4096] bf16
// blocks [4096,8192):  Bcat[c][colOff+r] = bf16(src[r][c]) (32x32 LDS transpose)
// blocks [8192,10240): Cwbf[o][h] = bf16(Cr*wr - Ci*wi), w recomputed inline
// block 0 additionally zeroes the 64 split-K tile counters.

__global__ void prep_kernel(const float* __restrict__ Cr, const float* __restrict__ Ci,
                            const float* __restrict__ Br, const float* __restrict__ Bi,
                            const float* __restrict__ v_log, const float* __restrict__ th_log,
                            u16* __restrict__ Ccat, u16* __restrict__ Bcat,
                            u16* __restrict__ Cwbf, int* __restrict__ cnt)
{
    __shared__ float t[32][33];
    const int b = blockIdx.x, tid = threadIdx.x;
    if (b == 0 && tid < 64) cnt[tid] = 0;

    if (b < 4096) {
        // ---- pack Ccat = [Cr | -Ci] ----
        int i = b * 256 + tid;
        int e = i * 4;
        int o = e >> 12;
        int k = e & 4095;
        float4 f; float s;
        if (k < 2048) { f = *(const float4*)(Cr + (size_t)o * 2048 + k);          s =  1.f; }
        else          { f = *(const float4*)(Ci + (size_t)o * 2048 + (k - 2048)); s = -1.f; }
        ushort4 u;
        u.x = f32_to_bf16(s * f.x); u.y = f32_to_bf16(s * f.y);
        u.z = f32_to_bf16(s * f.z); u.w = f32_to_bf16(s * f.w);
        ((ushort4*)Ccat)[i] = u;
    } else if (b < 8192) {
        // ---- transpose-cast Bcat = [Br^T | Bi^T] ----
        int b2 = b - 4096;
        const float* src = (b2 & 2048) ? Bi : Br;
        int colOff = (b2 & 2048) ? 2048 : 0;
        int c0 = (b2 & 31) * 32, r0 = ((b2 >> 5) & 63) * 32;
        int tx = tid & 31, ty = tid >> 5;   // 32 x 8
#pragma unroll
        for (int j = 0; j < 4; j++)
            t[ty + j * 8][tx] = src[(size_t)(r0 + ty + j * 8) * 1024 + c0 + tx];
        __syncthreads();
#pragma unroll
        for (int j = 0; j < 4; j++)
            Bcat[(size_t)(c0 + ty + j * 8) * 4096 + colOff + r0 + tx] =
                f32_to_bf16(t[tx][ty + j * 8]);
    } else {
        // ---- Cwbf = bf16(Cr*wr - Ci*wi); w recomputed per element (cheap trans) ----
        int j = (b - 8192) * 256 + tid;
        int e = j * 4;
        int o = e >> 11;
        int h = e & 2047;
        float4 cr = *(const float4*)(Cr + (size_t)o * 2048 + h);
        float4 ci = *(const float4*)(Ci + (size_t)o * 2048 + h);
        float4 vl = *(const float4*)(v_log + h);
        float4 tl = *(const float4*)(th_log + h);
        float mag, ang, wr, wi;
        ushort4 u;
        mag = expf(-expf(vl.x)); ang = expf(tl.x); wr = mag * cosf(ang); wi = mag * sinf(ang);
        u.x = f32_to_bf16(cr.x * wr - ci.x * wi);
        mag = expf(-expf(vl.y)); ang = expf(tl.y); wr = mag * cosf(ang); wi = mag * sinf(ang);
        u.y = f32_to_bf16(cr.y * wr - ci.y * wi);
        mag = expf(-expf(vl.z)); ang = expf(tl.z); wr = mag * cosf(ang); wi = mag * sinf(ang);
        u.z = f32_to_bf16(cr.z * wr - ci.z * wi);
        mag = expf(-expf(vl.w)); ang = expf(tl.w); wr = mag * cosf(ang); wi = mag * sinf(ang);
        u.w = f32_to_bf16(cr.w * wr - ci.w * wi);
        ((ushort4*)Cwbf)[j] = u;
    }
}

// merged cast: dst[0..16MB) = bf16(x), dst[16MB..48MB) = bf16(h_prev) (adjacent)
__global__ void cast_both_kernel(const float* __restrict__ x,
                                 const float* __restrict__ h_prev,
                                 u16* __restrict__ dst) {
    const int n4x = 8192 * 1024 / 4;     // 2097152
    int i = blockIdx.x * blockDim.x + threadIdx.x;
    float4 f = (i < n4x) ? ((const float4*)x)[i] : ((const float4*)h_prev)[i - n4x];
    ushort4 o;
    o.x = f32_to_bf16(f.x); o.y = f32_to_bf16(f.y);
    o.z = f32_to_bf16(f.z); o.w = f32_to_bf16(f.w);
    ((ushort4*)dst)[i] = o;
}

// ---------------- weight GEMM: split-K=8, 128x128 tile, BK=64 ----------------
// partials[bz][m][n] = sum_{k in 512-chunk bz} Ccat[m][k] * Bcat[n][k], K=4096.
// Semaphore tail: the 8th block per (bm,bn) tile sums all 8 partials (z order
// 0..7, identical rounding to the old reduce pass) and writes bf16 Wmain.

__global__ __launch_bounds__(256)
void gemm_splitk_kernel(const u16* __restrict__ A, const u16* __restrict__ B,
                        float* __restrict__ partials, u16* __restrict__ Wmain,
                        int* __restrict__ cnt)
{
    __shared__ __align__(16) u16 ldsA[128 * 64];
    __shared__ __align__(16) u16 ldsB[128 * 64];
    __shared__ int lastFlag;
    const int K = 4096;

    const int tid = threadIdx.x, wid = tid >> 6, lane = tid & 63;
    const int quad = lane >> 4, l16 = lane & 15;
    const int wm = wid >> 1, wn = wid & 1;
    const int bm = blockIdx.y, bn = blockIdx.x, bz = blockIdx.z;
    const int kb = bz * 512;

    const u16* gA[4]; const u16* gB[4];
    u16 *lA[4], *lB[4];
#pragma unroll
    for (int t = 0; t < 4; t++) {
        int s = wid * 256 + t * 64 + lane;
        int sr = s >> 3;
        int sj = (s & 7) ^ (sr & 7);
        lA[t] = ldsA + s * 8;
        lB[t] = ldsB + s * 8;
        gA[t] = A + (size_t)(bm * 128 + sr) * K + sj * 8 + kb;
        gB[t] = B + (size_t)(bn * 128 + sr) * K + sj * 8 + kb;
    }

    const f32x4 fz = {0.f, 0.f, 0.f, 0.f};
    f32x4 acc[4][4];
#pragma unroll
    for (int i = 0; i < 4; i++)
#pragma unroll
        for (int j = 0; j < 4; j++) acc[i][j] = fz;

    for (int k0 = 0; k0 < 512; k0 += 64) {
        __syncthreads();
#pragma unroll
        for (int t = 0; t < 4; t++) {
            gld_lds16(gA[t] + k0, lA[t]);
            gld_lds16(gB[t] + k0, lB[t]);
        }
        __syncthreads();
#pragma unroll
        for (int ks = 0; ks < 2; ks++) {
            bf16x8 af[4], bfr[4];
#pragma unroll
            for (int i = 0; i < 4; i++) {
                int r = wm * 64 + i * 16 + l16;
                af[i] = *(const bf16x8*)(ldsA + (r * 8 + ((ks * 4 + quad) ^ (r & 7))) * 8);
            }
#pragma unroll
            for (int j = 0; j < 4; j++) {
                int r = wn * 64 + j * 16 + l16;
                bfr[j] = *(const bf16x8*)(ldsB + (r * 8 + ((ks * 4 + quad) ^ (r & 7))) * 8);
            }
#pragma unroll
            for (int i = 0; i < 4; i++)
#pragma unroll
                for (int j = 0; j < 4; j++)
                    acc[i][j] = __builtin_amdgcn_mfma_f32_16x16x32_bf16(af[i], bfr[j], acc[i][j], 0, 0, 0);
        }
    }

    float* P = partials + ((size_t)bz << 20);
    const int gm = bm * 128 + wm * 64, gn = bn * 128 + wn * 64;
#pragma unroll
    for (int i = 0; i < 4; i++)
#pragma unroll
        for (int j = 0; j < 4; j++) {
            int col = gn + j * 16 + l16;
#pragma unroll
            for (int r = 0; r < 4; r++)
                P[(size_t)(gm + i * 16 + quad * 4 + r) * 1024 + col] = acc[i][j][r];
        }

    // ---- semaphore tail: last block per tile reduces 8 partials -> bf16 Wmain ----
    __threadfence();                              // release: partial stores visible
    __syncthreads();                              // all threads' stores fenced
    if (tid == 0)
        lastFlag = (atomicAdd(&cnt[bm * 8 + bn], 1) == 7);
    __syncthreads();
    if (!lastFlag) return;
    __threadfence();                              // acquire: order loads after count

#pragma unroll
    for (int i = 0; i < 4; i++)
#pragma unroll
        for (int j = 0; j < 4; j++) {
            int col = gn + j * 16 + l16;
#pragma unroll
            for (int r = 0; r < 4; r++) {
                size_t off = (size_t)(gm + i * 16 + quad * 4 + r) * 1024 + col;
                float s = 0.f;
#pragma unroll
                for (int z = 0; z < 8; z++)
                    s += partials[((size_t)z << 20) + off];
                Wmain[off] = f32_to_bf16(s);
            }
        }
}

// ---------------- main GEMM ----------------
// out[8192,1024] = [x_bf | hp_bf] @ [Wmain | Cwbf]^T, two K-phases, 128x128 tile, BK=64.
// 1D grid of 512; bm = id&63 so the 8 blocks sharing an A-tile share id%8 (same XCD).

__global__ __launch_bounds__(256)
void gemm_main_kernel(const u16* __restrict__ Axb, const u16* __restrict__ Ahb,
                      const u16* __restrict__ Bw,  const u16* __restrict__ Bcw,
                      float* __restrict__ out)
{
    __shared__ __align__(16) u16 ldsA[128 * 64];
    __shared__ __align__(16) u16 ldsB[128 * 64];

    const int tid = threadIdx.x, wid = tid >> 6, lane = tid & 63;
    const int quad = lane >> 4, l16 = lane & 15;
    const int wm = wid >> 1, wn = wid & 1;
    const int id = blockIdx.x;
    const int bm = id & 63, bn = id >> 6;

    int srow[4], sj[4];
    u16 *lA[4], *lB[4];
#pragma unroll
    for (int t = 0; t < 4; t++) {
        int s = wid * 256 + t * 64 + lane;
        srow[t] = s >> 3;
        sj[t] = (s & 7) ^ (srow[t] & 7);
        lA[t] = ldsA + s * 8;
        lB[t] = ldsB + s * 8;
    }

    const f32x4 fz = {0.f, 0.f, 0.f, 0.f};
    f32x4 acc[4][4];
#pragma unroll
    for (int i = 0; i < 4; i++)
#pragma unroll
        for (int j = 0; j < 4; j++) acc[i][j] = fz;

#pragma unroll 1
    for (int phase = 0; phase < 2; phase++) {
        const u16* Ap = phase ? Ahb : Axb;
        const u16* Bp = phase ? Bcw : Bw;
        const int KS = phase ? 2048 : 1024;
        const u16* gA[4]; const u16* gB[4];
#pragma unroll
        for (int t = 0; t < 4; t++) {
            gA[t] = Ap + (size_t)(bm * 128 + srow[t]) * KS + sj[t] * 8;
            gB[t] = Bp + (size_t)(bn * 128 + srow[t]) * KS + sj[t] * 8;
        }
        for (int k0 = 0; k0 < KS; k0 += 64) {
            __syncthreads();
#pragma unroll
            for (int t = 0; t < 4; t++) {
                gld_lds16(gA[t] + k0, lA[t]);
                gld_lds16(gB[t] + k0, lB[t]);
            }
            __syncthreads();
#pragma unroll
            for (int ks = 0; ks < 2; ks++) {
                bf16x8 af[4], bfr[4];
#pragma unroll
                for (int i = 0; i < 4; i++) {
                    int r = wm * 64 + i * 16 + l16;
                    af[i] = *(const bf16x8*)(ldsA + (r * 8 + ((ks * 4 + quad) ^ (r & 7))) * 8);
                }
#pragma unroll
                for (int j = 0; j < 4; j++) {
                    int r = wn * 64 + j * 16 + l16;
                    bfr[j] = *(const bf16x8*)(ldsB + (r * 8 + ((ks * 4 + quad) ^ (r & 7))) * 8);
                }
#pragma unroll
                for (int i = 0; i < 4; i++)
#pragma unroll
                    for (int j = 0; j < 4; j++)
                        acc[i][j] = __builtin_amdgcn_mfma_f32_16x16x32_bf16(af[i], bfr[j], acc[i][j], 0, 0, 0);
            }
        }
    }

    const int gm = bm * 128 + wm * 64, gn = bn * 128 + wn * 64;
#pragma unroll
    for (int i = 0; i < 4; i++)
#pragma unroll
        for (int j = 0; j < 4; j++) {
            int col = gn + j * 16 + l16;
#pragma unroll
            for (int r = 0; r < 4; r++)
                out[(size_t)(gm + i * 16 + quad * 4 + r) * 1024 + col] = acc[i][j][r];
        }
}

// ---------------- launch ----------------

extern "C" void kernel_launch(void* const* d_in, const int* in_sizes, int n_in,
                              void* d_out, int out_size, void* d_ws, size_t ws_size,
                              hipStream_t stream)
{
    const float* x      = (const float*)d_in[0];
    const float* h_prev = (const float*)d_in[1];
    const float* Br     = (const float*)d_in[2];
    const float* Bi     = (const float*)d_in[3];
    const float* Cr     = (const float*)d_in[4];
    const float* Ci     = (const float*)d_in[5];
    const float* v_log  = (const float*)d_in[6];
    const float* th_log = (const float*)d_in[7];
    float* out = (float*)d_out;

    const size_t MB = 1024 * 1024;
    // region0 (48 MB): prep phase {Ccat 8 | Bcat 8 | partials 32}, then {x_bf 16 | hp_bf 32}
    size_t need = 54 * MB + 256;
    if (ws_size < need) return;

    char* ws = (char*)d_ws;
    u16*   Ccat     = (u16*)ws;                   // [1024,4096] bf16
    u16*   Bcat     = (u16*)(ws + 8 * MB);        // [1024,4096] bf16 = [BrT|BiT]
    float* partials = (float*)(ws + 16 * MB);     // [8][1024][1024] f32 (dead after splitk)
    u16*   x_bf     = (u16*)ws;                   // [8192,1024] bf16 (aliases Ccat/Bcat)
    u16*   hp_bf    = (u16*)(ws + 16 * MB);       // [8192,2048] bf16 (aliases partials)
    u16*   Wmain    = (u16*)(ws + 48 * MB);       // [1024,1024] bf16
    u16*   Cwbf     = (u16*)(ws + 50 * MB);       // [1024,2048] bf16
    int*   cnt      = (int*)(ws + 54 * MB);       // [64] split-K tile counters

    // 1) prep: Ccat=[Cr|-Ci], Bcat=[Br^T|Bi^T], Cwbf=bf16(Cr*wr-Ci*wi), zero counters
    prep_kernel<<<10240, 256, 0, stream>>>(Cr, Ci, Br, Bi, v_log, th_log,
                                           Ccat, Bcat, Cwbf, cnt);
    // 2) Wmain = bf16(Ccat @ Bcat^T) — split-K=8 with in-kernel semaphore reduction
    gemm_splitk_kernel<<<dim3(8, 8, 8), 256, 0, stream>>>(Ccat, Bcat, partials, Wmain, cnt);
    // 3) [x | h_prev] -> bf16 (overwrites prep buffers — consumed)
    cast_both_kernel<<<24576, 256, 0, stream>>>(x, h_prev, x_bf);
    // 4) out = [x_bf | hp_bf] @ [Wmain | Cwbf]^T
    gemm_main_kernel<<<512, 256, 0, stream>>>(x_bf, hp_bf, Wmain, Cwbf, out);
}

// Round 2
// 246.240 us; speedup vs baseline: 1.3075x; 1.3075x over previous
//
#include <hip/hip_runtime.h>
#include <stdint.h>

typedef unsigned short u16;
typedef short bf16x8 __attribute__((ext_vector_type(8)));   // 8 bf16 in 4 VGPRs
typedef float f32x4 __attribute__((ext_vector_type(4)));

typedef void as1_void __attribute__((address_space(1)));
typedef void as3_void __attribute__((address_space(3)));

__device__ inline u16 f32_to_bf16(float f) {
    uint32_t u = __builtin_bit_cast(uint32_t, f);
    u += 0x7fffu + ((u >> 16) & 1u);   // RNE (finite values only)
    return (u16)(u >> 16);
}

__device__ inline void gld_lds16(const void* g, void* l) {
    // async global->LDS, 16B/lane; HW dest = wave-uniform base + lane*16
    __builtin_amdgcn_global_load_lds((as1_void*)g, (as3_void*)l, 16, 0, 0);
}

// LDS tile layout (both GEMMs): 128 rows x 64 cols bf16, stored as 1024 chunks of
// 16B. Global (row, colchunk j) lives at chunk slot row*8 + (j ^ (row&7)).
// The XOR swizzle spreads same-column frag reads across all 32 banks (2-way max,
// free per m136) while keeping each staging issue 64 lane-contiguous slots.

// ---------------- merged prep kernel ----------------
// blocks [0,4096):     Ccat[o][k] = [Cr | -Ci]  row-major [1024][4096] bf16
// blocks [4096,8192):  Bcat[c][colOff+r] = bf16(src[r][c]) (32x32 LDS transpose)
// blocks [8192,10240): Cwbf[o][h] = bf16(Cr*wr - Ci*wi), w recomputed inline

__global__ void prep_kernel(const float* __restrict__ Cr, const float* __restrict__ Ci,
                            const float* __restrict__ Br, const float* __restrict__ Bi,
                            const float* __restrict__ v_log, const float* __restrict__ th_log,
                            u16* __restrict__ Ccat, u16* __restrict__ Bcat,
                            u16* __restrict__ Cwbf)
{
    __shared__ float t[32][33];
    const int b = blockIdx.x, tid = threadIdx.x;

    if (b < 4096) {
        // ---- pack Ccat = [Cr | -Ci] ----
        int i = b * 256 + tid;
        int e = i * 4;
        int o = e >> 12;
        int k = e & 4095;
        float4 f; float s;
        if (k < 2048) { f = *(const float4*)(Cr + (size_t)o * 2048 + k);          s =  1.f; }
        else          { f = *(const float4*)(Ci + (size_t)o * 2048 + (k - 2048)); s = -1.f; }
        ushort4 u;
        u.x = f32_to_bf16(s * f.x); u.y = f32_to_bf16(s * f.y);
        u.z = f32_to_bf16(s * f.z); u.w = f32_to_bf16(s * f.w);
        ((ushort4*)Ccat)[i] = u;
    } else if (b < 8192) {
        // ---- transpose-cast Bcat = [Br^T | Bi^T] ----
        int b2 = b - 4096;
        const float* src = (b2 & 2048) ? Bi : Br;
        int colOff = (b2 & 2048) ? 2048 : 0;
        int c0 = (b2 & 31) * 32, r0 = ((b2 >> 5) & 63) * 32;
        int tx = tid & 31, ty = tid >> 5;   // 32 x 8
#pragma unroll
        for (int j = 0; j < 4; j++)
            t[ty + j * 8][tx] = src[(size_t)(r0 + ty + j * 8) * 1024 + c0 + tx];
        __syncthreads();
#pragma unroll
        for (int j = 0; j < 4; j++)
            Bcat[(size_t)(c0 + ty + j * 8) * 4096 + colOff + r0 + tx] =
                f32_to_bf16(t[tx][ty + j * 8]);
    } else {
        // ---- Cwbf = bf16(Cr*wr - Ci*wi); w recomputed per element (cheap trans) ----
        int j = (b - 8192) * 256 + tid;
        int e = j * 4;
        int o = e >> 11;
        int h = e & 2047;
        float4 cr = *(const float4*)(Cr + (size_t)o * 2048 + h);
        float4 ci = *(const float4*)(Ci + (size_t)o * 2048 + h);
        float4 vl = *(const float4*)(v_log + h);
        float4 tl = *(const float4*)(th_log + h);
        float mag, ang, wr, wi;
        ushort4 u;
        mag = expf(-expf(vl.x)); ang = expf(tl.x); wr = mag * cosf(ang); wi = mag * sinf(ang);
        u.x = f32_to_bf16(cr.x * wr - ci.x * wi);
        mag = expf(-expf(vl.y)); ang = expf(tl.y); wr = mag * cosf(ang); wi = mag * sinf(ang);
        u.y = f32_to_bf16(cr.y * wr - ci.y * wi);
        mag = expf(-expf(vl.z)); ang = expf(tl.z); wr = mag * cosf(ang); wi = mag * sinf(ang);
        u.z = f32_to_bf16(cr.z * wr - ci.z * wi);
        mag = expf(-expf(vl.w)); ang = expf(tl.w); wr = mag * cosf(ang); wi = mag * sinf(ang);
        u.w = f32_to_bf16(cr.w * wr - ci.w * wi);
        ((ushort4*)Cwbf)[j] = u;
    }
}

// ---------------- reduce + cast (merged; big-workspace path) ----------------
// blocks [0,1024):        Wmain = bf16(sum_z partials[z]) (z order 0..7, same rounding)
// blocks [1024,9216):     x_bf  = bf16(x)
// blocks [9216,25600):    hp_bf = bf16(h_prev)
// Safe because this launches AFTER splitk (stream order = the fence) and hp_bf
// does NOT alias partials in this layout.

__global__ void reduce_cast_kernel(const float* __restrict__ partials,
                                   const float* __restrict__ x,
                                   const float* __restrict__ h_prev,
                                   u16* __restrict__ Wmain,
                                   u16* __restrict__ x_bf,
                                   u16* __restrict__ hp_bf)
{
    const int b = blockIdx.x, tid = threadIdx.x;
    if (b < 1024) {
        int i = b * 256 + tid;
        int e = i * 4;
        float4 s = *(const float4*)(partials + e);
#pragma unroll
        for (int z = 1; z < 8; z++) {
            float4 p = *(const float4*)(partials + ((size_t)z << 20) + e);
            s.x += p.x; s.y += p.y; s.z += p.z; s.w += p.w;
        }
        ushort4 u;
        u.x = f32_to_bf16(s.x); u.y = f32_to_bf16(s.y);
        u.z = f32_to_bf16(s.z); u.w = f32_to_bf16(s.w);
        ((ushort4*)Wmain)[i] = u;
    } else if (b < 9216) {
        int i = (b - 1024) * 256 + tid;
        float4 f = ((const float4*)x)[i];
        ushort4 o;
        o.x = f32_to_bf16(f.x); o.y = f32_to_bf16(f.y);
        o.z = f32_to_bf16(f.z); o.w = f32_to_bf16(f.w);
        ((ushort4*)x_bf)[i] = o;
    } else {
        int i = (b - 9216) * 256 + tid;
        float4 f = ((const float4*)h_prev)[i];
        ushort4 o;
        o.x = f32_to_bf16(f.x); o.y = f32_to_bf16(f.y);
        o.z = f32_to_bf16(f.z); o.w = f32_to_bf16(f.w);
        ((ushort4*)hp_bf)[i] = o;
    }
}

// ---------------- small-workspace fallbacks (round-0 proven) ----------------

__global__ void reduce_only_kernel(const float* __restrict__ partials,
                                   u16* __restrict__ Wmain) {
    int i = blockIdx.x * blockDim.x + threadIdx.x;   // 1024 blocks x 256
    int e = i * 4;
    float4 s = *(const float4*)(partials + e);
#pragma unroll
    for (int z = 1; z < 8; z++) {
        float4 p = *(const float4*)(partials + ((size_t)z << 20) + e);
        s.x += p.x; s.y += p.y; s.z += p.z; s.w += p.w;
    }
    ushort4 u;
    u.x = f32_to_bf16(s.x); u.y = f32_to_bf16(s.y);
    u.z = f32_to_bf16(s.z); u.w = f32_to_bf16(s.w);
    ((ushort4*)Wmain)[i] = u;
}

// merged cast: dst[0..16MB) = bf16(x), dst[16MB..48MB) = bf16(h_prev) (adjacent)
__global__ void cast_both_kernel(const float* __restrict__ x,
                                 const float* __restrict__ h_prev,
                                 u16* __restrict__ dst) {
    const int n4x = 8192 * 1024 / 4;     // 2097152
    int i = blockIdx.x * blockDim.x + threadIdx.x;
    float4 f = (i < n4x) ? ((const float4*)x)[i] : ((const float4*)h_prev)[i - n4x];
    ushort4 o;
    o.x = f32_to_bf16(f.x); o.y = f32_to_bf16(f.y);
    o.z = f32_to_bf16(f.z); o.w = f32_to_bf16(f.w);
    ((ushort4*)dst)[i] = o;
}

// ---------------- weight GEMM: split-K=8, 128x128 tile, BK=64 ----------------
// partials[bz][m][n] = sum_{k in 512-chunk bz} Ccat[m][k] * Bcat[n][k], K=4096
// NO in-kernel reduction tail: cross-XCD partials hand-off goes through the
// dispatch boundary (round-1 lesson: device-scope fence per block = 4x slowdown).

__global__ __launch_bounds__(256)
void gemm_splitk_kernel(const u16* __restrict__ A, const u16* __restrict__ B,
                        float* __restrict__ partials)
{
    __shared__ __align__(16) u16 ldsA[128 * 64];
    __shared__ __align__(16) u16 ldsB[128 * 64];
    const int K = 4096;

    const int tid = threadIdx.x, wid = tid >> 6, lane = tid & 63;
    const int quad = lane >> 4, l16 = lane & 15;
    const int wm = wid >> 1, wn = wid & 1;
    const int bm = blockIdx.y, bn = blockIdx.x, bz = blockIdx.z;
    const int kb = bz * 512;

    const u16* gA[4]; const u16* gB[4];
    u16 *lA[4], *lB[4];
#pragma unroll
    for (int t = 0; t < 4; t++) {
        int s = wid * 256 + t * 64 + lane;
        int sr = s >> 3;
        int sj = (s & 7) ^ (sr & 7);
        lA[t] = ldsA + s * 8;
        lB[t] = ldsB + s * 8;
        gA[t] = A + (size_t)(bm * 128 + sr) * K + sj * 8 + kb;
        gB[t] = B + (size_t)(bn * 128 + sr) * K + sj * 8 + kb;
    }

    const f32x4 fz = {0.f, 0.f, 0.f, 0.f};
    f32x4 acc[4][4];
#pragma unroll
    for (int i = 0; i < 4; i++)
#pragma unroll
        for (int j = 0; j < 4; j++) acc[i][j] = fz;

    for (int k0 = 0; k0 < 512; k0 += 64) {
        __syncthreads();
#pragma unroll
        for (int t = 0; t < 4; t++) {
            gld_lds16(gA[t] + k0, lA[t]);
            gld_lds16(gB[t] + k0, lB[t]);
        }
        __syncthreads();
#pragma unroll
        for (int ks = 0; ks < 2; ks++) {
            bf16x8 af[4], bfr[4];
#pragma unroll
            for (int i = 0; i < 4; i++) {
                int r = wm * 64 + i * 16 + l16;
                af[i] = *(const bf16x8*)(ldsA + (r * 8 + ((ks * 4 + quad) ^ (r & 7))) * 8);
            }
#pragma unroll
            for (int j = 0; j < 4; j++) {
                int r = wn * 64 + j * 16 + l16;
                bfr[j] = *(const bf16x8*)(ldsB + (r * 8 + ((ks * 4 + quad) ^ (r & 7))) * 8);
            }
#pragma unroll
            for (int i = 0; i < 4; i++)
#pragma unroll
                for (int j = 0; j < 4; j++)
                    acc[i][j] = __builtin_amdgcn_mfma_f32_16x16x32_bf16(af[i], bfr[j], acc[i][j], 0, 0, 0);
        }
    }

    float* P = partials + ((size_t)bz << 20);
    const int gm = bm * 128 + wm * 64, gn = bn * 128 + wn * 64;
#pragma unroll
    for (int i = 0; i < 4; i++)
#pragma unroll
        for (int j = 0; j < 4; j++) {
            int col = gn + j * 16 + l16;
#pragma unroll
            for (int r = 0; r < 4; r++)
                P[(size_t)(gm + i * 16 + quad * 4 + r) * 1024 + col] = acc[i][j][r];
        }
}

// ---------------- main GEMM ----------------
// out[8192,1024] = [x_bf | hp_bf] @ [Wmain | Cwbf]^T, two K-phases, 128x128 tile, BK=64.
// 1D grid of 512; bm = id&63 so the 8 blocks sharing an A-tile share id%8 (same XCD).

__global__ __launch_bounds__(256)
void gemm_main_kernel(const u16* __restrict__ Axb, const u16* __restrict__ Ahb,
                      const u16* __restrict__ Bw,  const u16* __restrict__ Bcw,
                      float* __restrict__ out)
{
    __shared__ __align__(16) u16 ldsA[128 * 64];
    __shared__ __align__(16) u16 ldsB[128 * 64];

    const int tid = threadIdx.x, wid = tid >> 6, lane = tid & 63;
    const int quad = lane >> 4, l16 = lane & 15;
    const int wm = wid >> 1, wn = wid & 1;
    const int id = blockIdx.x;
    const int bm = id & 63, bn = id >> 6;

    int srow[4], sj[4];
    u16 *lA[4], *lB[4];
#pragma unroll
    for (int t = 0; t < 4; t++) {
        int s = wid * 256 + t * 64 + lane;
        srow[t] = s >> 3;
        sj[t] = (s & 7) ^ (srow[t] & 7);
        lA[t] = ldsA + s * 8;
        lB[t] = ldsB + s * 8;
    }

    const f32x4 fz = {0.f, 0.f, 0.f, 0.f};
    f32x4 acc[4][4];
#pragma unroll
    for (int i = 0; i < 4; i++)
#pragma unroll
        for (int j = 0; j < 4; j++) acc[i][j] = fz;

#pragma unroll 1
    for (int phase = 0; phase < 2; phase++) {
        const u16* Ap = phase ? Ahb : Axb;
        const u16* Bp = phase ? Bcw : Bw;
        const int KS = phase ? 2048 : 1024;
        const u16* gA[4]; const u16* gB[4];
#pragma unroll
        for (int t = 0; t < 4; t++) {
            gA[t] = Ap + (size_t)(bm * 128 + srow[t]) * KS + sj[t] * 8;
            gB[t] = Bp + (size_t)(bn * 128 + srow[t]) * KS + sj[t] * 8;
        }
        for (int k0 = 0; k0 < KS; k0 += 64) {
            __syncthreads();
#pragma unroll
            for (int t = 0; t < 4; t++) {
                gld_lds16(gA[t] + k0, lA[t]);
                gld_lds16(gB[t] + k0, lB[t]);
            }
            __syncthreads();
#pragma unroll
            for (int ks = 0; ks < 2; ks++) {
                bf16x8 af[4], bfr[4];
#pragma unroll
                for (int i = 0; i < 4; i++) {
                    int r = wm * 64 + i * 16 + l16;
                    af[i] = *(const bf16x8*)(ldsA + (r * 8 + ((ks * 4 + quad) ^ (r & 7))) * 8);
                }
#pragma unroll
                for (int j = 0; j < 4; j++) {
                    int r = wn * 64 + j * 16 + l16;
                    bfr[j] = *(const bf16x8*)(ldsB + (r * 8 + ((ks * 4 + quad) ^ (r & 7))) * 8);
                }
#pragma unroll
                for (int i = 0; i < 4; i++)
#pragma unroll
                    for (int j = 0; j < 4; j++)
                        acc[i][j] = __builtin_amdgcn_mfma_f32_16x16x32_bf16(af[i], bfr[j], acc[i][j], 0, 0, 0);
            }
        }
    }

    const int gm = bm * 128 + wm * 64, gn = bn * 128 + wn * 64;
#pragma unroll
    for (int i = 0; i < 4; i++)
#pragma unroll
        for (int j = 0; j < 4; j++) {
            int col = gn + j * 16 + l16;
#pragma unroll
            for (int r = 0; r < 4; r++)
                out[(size_t)(gm + i * 16 + quad * 4 + r) * 1024 + col] = acc[i][j][r];
        }
}

// ---------------- launch ----------------

extern "C" void kernel_launch(void* const* d_in, const int* in_sizes, int n_in,
                              void* d_out, int out_size, void* d_ws, size_t ws_size,
                              hipStream_t stream)
{
    const float* x      = (const float*)d_in[0];
    const float* h_prev = (const float*)d_in[1];
    const float* Br     = (const float*)d_in[2];
    const float* Bi     = (const float*)d_in[3];
    const float* Cr     = (const float*)d_in[4];
    const float* Ci     = (const float*)d_in[5];
    const float* v_log  = (const float*)d_in[6];
    const float* th_log = (const float*)d_in[7];
    float* out = (float*)d_out;

    const size_t MB = 1024 * 1024;
    if (ws_size < 54 * MB) return;
    const bool big = (ws_size >= 86 * MB);   // non-aliased hp_bf -> 4-dispatch path

    char* ws = (char*)d_ws;
    u16*   Ccat     = (u16*)ws;                   // [1024,4096] bf16
    u16*   Bcat     = (u16*)(ws + 8 * MB);        // [1024,4096] bf16 = [BrT|BiT]
    float* partials = (float*)(ws + 16 * MB);     // [8][1024][1024] f32
    u16*   x_bf     = (u16*)ws;                   // [8192,1024] bf16 (aliases Ccat/Bcat, dead)
    u16*   Wmain    = (u16*)(ws + 48 * MB);       // [1024,1024] bf16
    u16*   Cwbf     = (u16*)(ws + 50 * MB);       // [1024,2048] bf16
    // hp_bf: big path = fresh region above 54MB (partials stay live during casts);
    //        small path = round-0 aliasing over partials (reduce must finish first).
    u16*   hp_bf    = big ? (u16*)(ws + 54 * MB) : (u16*)(ws + 16 * MB);

    // 1) prep: Ccat=[Cr|-Ci], Bcat=[Br^T|Bi^T], Cwbf=bf16(Cr*wr-Ci*wi)
    prep_kernel<<<10240, 256, 0, stream>>>(Cr, Ci, Br, Bi, v_log, th_log,
                                           Ccat, Bcat, Cwbf);
    // 2) partials = Ccat @ Bcat^T (split-K=8, 512 blocks, no tail)
    gemm_splitk_kernel<<<dim3(8, 8, 8), 256, 0, stream>>>(Ccat, Bcat, partials);
    // 3) Wmain = bf16(sum partials); x/h_prev -> bf16
    if (big) {
        reduce_cast_kernel<<<25600, 256, 0, stream>>>(partials, x, h_prev,
                                                      Wmain, x_bf, hp_bf);
    } else {
        reduce_only_kernel<<<1024, 256, 0, stream>>>(partials, Wmain);
        cast_both_kernel<<<24576, 256, 0, stream>>>(x, h_prev, x_bf);
    }
    // 4) out = [x_bf | hp_bf] @ [Wmain | Cwbf]^T
    gemm_main_kernel<<<512, 256, 0, stream>>>(x_bf, hp_bf, Wmain, Cwbf, out);
}

// Round 3
// 246.223 us; speedup vs baseline: 1.3076x; 1.0001x over previous
//
#include <hip/hip_runtime.h>
#include <stdint.h>

typedef unsigned short u16;
typedef short bf16x8 __attribute__((ext_vector_type(8)));   // 8 bf16 in 4 VGPRs
typedef float f32x4 __attribute__((ext_vector_type(4)));

typedef void as1_void __attribute__((address_space(1)));
typedef void as3_void __attribute__((address_space(3)));

__device__ inline u16 f32_to_bf16(float f) {
    uint32_t u = __builtin_bit_cast(uint32_t, f);
    u += 0x7fffu + ((u >> 16) & 1u);   // RNE (finite values only)
    return (u16)(u >> 16);
}

__device__ inline void gld_lds16(const void* g, void* l) {
    // async global->LDS, 16B/lane; HW dest = wave-uniform base + lane*16
    __builtin_amdgcn_global_load_lds((as1_void*)g, (as3_void*)l, 16, 0, 0);
}

// LDS tile layout (all GEMMs): R rows x 64 cols bf16, stored as R*8 chunks of
// 16B. Global (row, colchunk j) lives at chunk slot row*8 + (j ^ (row&7)).
// The XOR swizzle spreads same-column frag reads across all 32 banks (2-way max,
// free per m136) while keeping each staging issue 64 lane-contiguous slots.
// (Measured SQ_LDS_BANK_CONFLICT = 0 with this scheme.)

// ---------------- merged prep kernel ----------------
// blocks [0,4096):     Ccat[o][k] = [Cr | -Ci]  row-major [1024][4096] bf16
// blocks [4096,8192):  Bcat[c][colOff+r] = bf16(src[r][c]) (32x32 LDS transpose)
// blocks [8192,10240): Cwbf[o][h] = bf16(Cr*wr - Ci*wi), w recomputed inline

__global__ void prep_kernel(const float* __restrict__ Cr, const float* __restrict__ Ci,
                            const float* __restrict__ Br, const float* __restrict__ Bi,
                            const float* __restrict__ v_log, const float* __restrict__ th_log,
                            u16* __restrict__ Ccat, u16* __restrict__ Bcat,
                            u16* __restrict__ Cwbf)
{
    __shared__ float t[32][33];
    const int b = blockIdx.x, tid = threadIdx.x;

    if (b < 4096) {
        // ---- pack Ccat = [Cr | -Ci] ----
        int i = b * 256 + tid;
        int e = i * 4;
        int o = e >> 12;
        int k = e & 4095;
        float4 f; float s;
        if (k < 2048) { f = *(const float4*)(Cr + (size_t)o * 2048 + k);          s =  1.f; }
        else          { f = *(const float4*)(Ci + (size_t)o * 2048 + (k - 2048)); s = -1.f; }
        ushort4 u;
        u.x = f32_to_bf16(s * f.x); u.y = f32_to_bf16(s * f.y);
        u.z = f32_to_bf16(s * f.z); u.w = f32_to_bf16(s * f.w);
        ((ushort4*)Ccat)[i] = u;
    } else if (b < 8192) {
        // ---- transpose-cast Bcat = [Br^T | Bi^T] ----
        int b2 = b - 4096;
        const float* src = (b2 & 2048) ? Bi : Br;
        int colOff = (b2 & 2048) ? 2048 : 0;
        int c0 = (b2 & 31) * 32, r0 = ((b2 >> 5) & 63) * 32;
        int tx = tid & 31, ty = tid >> 5;   // 32 x 8
#pragma unroll
        for (int j = 0; j < 4; j++)
            t[ty + j * 8][tx] = src[(size_t)(r0 + ty + j * 8) * 1024 + c0 + tx];
        __syncthreads();
#pragma unroll
        for (int j = 0; j < 4; j++)
            Bcat[(size_t)(c0 + ty + j * 8) * 4096 + colOff + r0 + tx] =
                f32_to_bf16(t[tx][ty + j * 8]);
    } else {
        // ---- Cwbf = bf16(Cr*wr - Ci*wi); w recomputed per element (cheap trans) ----
        int j = (b - 8192) * 256 + tid;
        int e = j * 4;
        int o = e >> 11;
        int h = e & 2047;
        float4 cr = *(const float4*)(Cr + (size_t)o * 2048 + h);
        float4 ci = *(const float4*)(Ci + (size_t)o * 2048 + h);
        float4 vl = *(const float4*)(v_log + h);
        float4 tl = *(const float4*)(th_log + h);
        float mag, ang, wr, wi;
        ushort4 u;
        mag = expf(-expf(vl.x)); ang = expf(tl.x); wr = mag * cosf(ang); wi = mag * sinf(ang);
        u.x = f32_to_bf16(cr.x * wr - ci.x * wi);
        mag = expf(-expf(vl.y)); ang = expf(tl.y); wr = mag * cosf(ang); wi = mag * sinf(ang);
        u.y = f32_to_bf16(cr.y * wr - ci.y * wi);
        mag = expf(-expf(vl.z)); ang = expf(tl.z); wr = mag * cosf(ang); wi = mag * sinf(ang);
        u.z = f32_to_bf16(cr.z * wr - ci.z * wi);
        mag = expf(-expf(vl.w)); ang = expf(tl.w); wr = mag * cosf(ang); wi = mag * sinf(ang);
        u.w = f32_to_bf16(cr.w * wr - ci.w * wi);
        ((ushort4*)Cwbf)[j] = u;
    }
}

// ---------------- reduce + cast (merged; big-workspace path) ----------------
// blocks [0,1024):        Wmain = bf16(sum_z partials[z]) (z order 0..7, same rounding)
// blocks [1024,9216):     x_bf  = bf16(x)
// blocks [9216,25600):    hp_bf = bf16(h_prev)
// Safe because this launches AFTER splitk (stream order = the fence) and hp_bf
// does NOT alias partials in this layout.

__global__ void reduce_cast_kernel(const float* __restrict__ partials,
                                   const float* __restrict__ x,
                                   const float* __restrict__ h_prev,
                                   u16* __restrict__ Wmain,
                                   u16* __restrict__ x_bf,
                                   u16* __restrict__ hp_bf)
{
    const int b = blockIdx.x, tid = threadIdx.x;
    if (b < 1024) {
        int i = b * 256 + tid;
        int e = i * 4;
        float4 s = *(const float4*)(partials + e);
#pragma unroll
        for (int z = 1; z < 8; z++) {
            float4 p = *(const float4*)(partials + ((size_t)z << 20) + e);
            s.x += p.x; s.y += p.y; s.z += p.z; s.w += p.w;
        }
        ushort4 u;
        u.x = f32_to_bf16(s.x); u.y = f32_to_bf16(s.y);
        u.z = f32_to_bf16(s.z); u.w = f32_to_bf16(s.w);
        ((ushort4*)Wmain)[i] = u;
    } else if (b < 9216) {
        int i = (b - 1024) * 256 + tid;
        float4 f = ((const float4*)x)[i];
        ushort4 o;
        o.x = f32_to_bf16(f.x); o.y = f32_to_bf16(f.y);
        o.z = f32_to_bf16(f.z); o.w = f32_to_bf16(f.w);
        ((ushort4*)x_bf)[i] = o;
    } else {
        int i = (b - 9216) * 256 + tid;
        float4 f = ((const float4*)h_prev)[i];
        ushort4 o;
        o.x = f32_to_bf16(f.x); o.y = f32_to_bf16(f.y);
        o.z = f32_to_bf16(f.z); o.w = f32_to_bf16(f.w);
        ((ushort4*)hp_bf)[i] = o;
    }
}

// ---------------- small-workspace fallbacks (round-0 proven) ----------------

__global__ void reduce_only_kernel(const float* __restrict__ partials,
                                   u16* __restrict__ Wmain) {
    int i = blockIdx.x * blockDim.x + threadIdx.x;   // 1024 blocks x 256
    int e = i * 4;
    float4 s = *(const float4*)(partials + e);
#pragma unroll
    for (int z = 1; z < 8; z++) {
        float4 p = *(const float4*)(partials + ((size_t)z << 20) + e);
        s.x += p.x; s.y += p.y; s.z += p.z; s.w += p.w;
    }
    ushort4 u;
    u.x = f32_to_bf16(s.x); u.y = f32_to_bf16(s.y);
    u.z = f32_to_bf16(s.z); u.w = f32_to_bf16(s.w);
    ((ushort4*)Wmain)[i] = u;
}

// merged cast: dst[0..16MB) = bf16(x), dst[16MB..48MB) = bf16(h_prev) (adjacent)
__global__ void cast_both_kernel(const float* __restrict__ x,
                                 const float* __restrict__ h_prev,
                                 u16* __restrict__ dst) {
    const int n4x = 8192 * 1024 / 4;     // 2097152
    int i = blockIdx.x * blockDim.x + threadIdx.x;
    float4 f = (i < n4x) ? ((const float4*)x)[i] : ((const float4*)h_prev)[i - n4x];
    ushort4 o;
    o.x = f32_to_bf16(f.x); o.y = f32_to_bf16(f.y);
    o.z = f32_to_bf16(f.z); o.w = f32_to_bf16(f.w);
    ((ushort4*)dst)[i] = o;
}

// ---------------- weight GEMM: split-K=8, 128x128 tile, BK=64 ----------------
// partials[bz][m][n] = sum_{k in 512-chunk bz} Ccat[m][k] * Bcat[n][k], K=4096
// NO in-kernel reduction tail: cross-XCD partials hand-off goes through the
// dispatch boundary (round-1 lesson: device-scope fence per block = 4x slowdown).

__global__ __launch_bounds__(256)
void gemm_splitk_kernel(const u16* __restrict__ A, const u16* __restrict__ B,
                        float* __restrict__ partials)
{
    __shared__ __align__(16) u16 ldsA[128 * 64];
    __shared__ __align__(16) u16 ldsB[128 * 64];
    const int K = 4096;

    const int tid = threadIdx.x, wid = tid >> 6, lane = tid & 63;
    const int quad = lane >> 4, l16 = lane & 15;
    const int wm = wid >> 1, wn = wid & 1;
    const int bm = blockIdx.y, bn = blockIdx.x, bz = blockIdx.z;
    const int kb = bz * 512;

    const u16* gA[4]; const u16* gB[4];
    u16 *lA[4], *lB[4];
#pragma unroll
    for (int t = 0; t < 4; t++) {
        int s = wid * 256 + t * 64 + lane;
        int sr = s >> 3;
        int sj = (s & 7) ^ (sr & 7);
        lA[t] = ldsA + s * 8;
        lB[t] = ldsB + s * 8;
        gA[t] = A + (size_t)(bm * 128 + sr) * K + sj * 8 + kb;
        gB[t] = B + (size_t)(bn * 128 + sr) * K + sj * 8 + kb;
    }

    const f32x4 fz = {0.f, 0.f, 0.f, 0.f};
    f32x4 acc[4][4];
#pragma unroll
    for (int i = 0; i < 4; i++)
#pragma unroll
        for (int j = 0; j < 4; j++) acc[i][j] = fz;

    for (int k0 = 0; k0 < 512; k0 += 64) {
        __syncthreads();
#pragma unroll
        for (int t = 0; t < 4; t++) {
            gld_lds16(gA[t] + k0, lA[t]);
            gld_lds16(gB[t] + k0, lB[t]);
        }
        __syncthreads();
#pragma unroll
        for (int ks = 0; ks < 2; ks++) {
            bf16x8 af[4], bfr[4];
#pragma unroll
            for (int i = 0; i < 4; i++) {
                int r = wm * 64 + i * 16 + l16;
                af[i] = *(const bf16x8*)(ldsA + (r * 8 + ((ks * 4 + quad) ^ (r & 7))) * 8);
            }
#pragma unroll
            for (int j = 0; j < 4; j++) {
                int r = wn * 64 + j * 16 + l16;
                bfr[j] = *(const bf16x8*)(ldsB + (r * 8 + ((ks * 4 + quad) ^ (r & 7))) * 8);
            }
#pragma unroll
            for (int i = 0; i < 4; i++)
#pragma unroll
                for (int j = 0; j < 4; j++)
                    acc[i][j] = __builtin_amdgcn_mfma_f32_16x16x32_bf16(af[i], bfr[j], acc[i][j], 0, 0, 0);
        }
    }

    float* P = partials + ((size_t)bz << 20);
    const int gm = bm * 128 + wm * 64, gn = bn * 128 + wn * 64;
#pragma unroll
    for (int i = 0; i < 4; i++)
#pragma unroll
        for (int j = 0; j < 4; j++) {
            int col = gn + j * 16 + l16;
#pragma unroll
            for (int r = 0; r < 4; r++)
                P[(size_t)(gm + i * 16 + quad * 4 + r) * 1024 + col] = acc[i][j][r];
        }
}

// ---------------- main GEMM (deep-pipelined) ----------------
// out[8192,1024] = [x_bf | hp_bf] @ [Wmain | Cwbf]^T, virtual K = 48 tiles of 64
// (tiles 0..15 from x@Wmain^T, 16..47 from hp@Cwbf^T — same accumulation order
// as the proven 128x128 kernel -> bit-identical numerics).
// BM=256 BN=128 BK=64, 512 thr (8 waves, 4Mx2N, per-wave 64x64 = same frag math
// as before). 3-deep LDS ring (144 KB), lookahead-2 staging, counted vmcnt(6)
// (never drain 0 in loop — T4), raw s_barrier + compiler fences, setprio around
// MFMA clusters (T5). Grid = 256 blocks = 1 block/CU; bm = id&31 so the 8
// bn-sharers of an A-strip are co-XCD (id%8 == bm%8).

__global__ __launch_bounds__(512)
void gemm_main_kernel(const u16* __restrict__ Axb, const u16* __restrict__ Ahb,
                      const u16* __restrict__ Bw,  const u16* __restrict__ Bcw,
                      float* __restrict__ out)
{
    // per buffer: A = 256x64 bf16 (16384 u16), B = 128x64 (8192 u16) at offset 16384
    __shared__ __align__(16) u16 lds[3][24576];

    const int tid = threadIdx.x, wid = tid >> 6, lane = tid & 63;
    const int quad = lane >> 4, l16 = lane & 15;
    const int wm = wid >> 1, wn = wid & 1;          // 4 M-waves x 2 N-waves
    const int id = blockIdx.x;
    const int bm = id & 31, bn = id >> 5;

    // staging slot geometry (per thread): A = 4 issues x 512 thr, B = 2 issues
    int srA[4], sjA[4], srB[2], sjB[2];
#pragma unroll
    for (int q = 0; q < 4; q++) {
        int s = q * 512 + tid;
        srA[q] = s >> 3;
        sjA[q] = (s & 7) ^ (srA[q] & 7);
    }
#pragma unroll
    for (int q = 0; q < 2; q++) {
        int s = q * 512 + tid;
        srB[q] = s >> 3;
        sjB[q] = (s & 7) ^ (srB[q] & 7);
    }

    u16* buf0 = &lds[0][0];
    u16* buf1 = &lds[1][0];
    u16* buf2 = &lds[2][0];

    const f32x4 fz = {0.f, 0.f, 0.f, 0.f};
    f32x4 acc[4][4];
#pragma unroll
    for (int i = 0; i < 4; i++)
#pragma unroll
        for (int j = 0; j < 4; j++) acc[i][j] = fz;

    // stage K-tile tt (0..47) into buf: 6 gld_lds per wave (4 A + 2 B)
    auto stage = [&](int tt, u16* buf) {
        const u16* Ab; const u16* Bb; int KS, koff;
        if (tt < 16) { Ab = Axb; Bb = Bw;  KS = 1024; koff = tt * 64; }
        else         { Ab = Ahb; Bb = Bcw; KS = 2048; koff = (tt - 16) * 64; }
#pragma unroll
        for (int q = 0; q < 4; q++)
            gld_lds16(Ab + (size_t)(bm * 256 + srA[q]) * KS + koff + sjA[q] * 8,
                      buf + (q * 512 + tid) * 8);
#pragma unroll
        for (int q = 0; q < 2; q++)
            gld_lds16(Bb + (size_t)(bn * 128 + srB[q]) * KS + koff + sjB[q] * 8,
                      buf + 16384 + (q * 512 + tid) * 8);
    };

    // compute one K-tile (32 MFMA/wave, ks = 0,1) from buf
    auto compute = [&](const u16* buf) {
#pragma unroll
        for (int ks = 0; ks < 2; ks++) {
            bf16x8 af[4], bfr[4];
#pragma unroll
            for (int i = 0; i < 4; i++) {
                int r = wm * 64 + i * 16 + l16;
                af[i] = *(const bf16x8*)(buf + (r * 8 + ((ks * 4 + quad) ^ (r & 7))) * 8);
            }
#pragma unroll
            for (int j = 0; j < 4; j++) {
                int r = wn * 64 + j * 16 + l16;
                bfr[j] = *(const bf16x8*)(buf + 16384 + (r * 8 + ((ks * 4 + quad) ^ (r & 7))) * 8);
            }
            __builtin_amdgcn_s_setprio(1);
#pragma unroll
            for (int i = 0; i < 4; i++)
#pragma unroll
                for (int j = 0; j < 4; j++)
                    acc[i][j] = __builtin_amdgcn_mfma_f32_16x16x32_bf16(af[i], bfr[j], acc[i][j], 0, 0, 0);
            __builtin_amdgcn_s_setprio(0);
        }
    };

#define PUBLISH(N)                                          \
    asm volatile("s_waitcnt vmcnt(" #N ")" ::: "memory");   \
    __builtin_amdgcn_s_barrier();                           \
    asm volatile("" ::: "memory")

    // prologue: stage tiles 0,1; publish tile 0 (tile 1 still in flight)
    stage(0, buf0);
    stage(1, buf1);
    PUBLISH(6);

    // steady state: 15 triples, tiles 0..44; stage lookahead-2 (tiles 2..46)
#pragma unroll 1
    for (int it = 0; it < 15; it++) {
        stage(3 * it + 2, buf2); compute(buf0); PUBLISH(6);
        stage(3 * it + 3, buf0); compute(buf1); PUBLISH(6);
        stage(3 * it + 4, buf1); compute(buf2); PUBLISH(6);
    }
    // tail: tiles 45 (buf0), 46 (buf1), 47 (buf2)
    stage(47, buf2); compute(buf0); PUBLISH(6);
    compute(buf1); PUBLISH(0);
    compute(buf2);
#undef PUBLISH

    const int gm = bm * 256 + wm * 64, gn = bn * 128 + wn * 64;
#pragma unroll
    for (int i = 0; i < 4; i++)
#pragma unroll
        for (int j = 0; j < 4; j++) {
            int col = gn + j * 16 + l16;
#pragma unroll
            for (int r = 0; r < 4; r++)
                out[(size_t)(gm + i * 16 + quad * 4 + r) * 1024 + col] = acc[i][j][r];
        }
}

// ---------------- launch ----------------

extern "C" void kernel_launch(void* const* d_in, const int* in_sizes, int n_in,
                              void* d_out, int out_size, void* d_ws, size_t ws_size,
                              hipStream_t stream)
{
    const float* x      = (const float*)d_in[0];
    const float* h_prev = (const float*)d_in[1];
    const float* Br     = (const float*)d_in[2];
    const float* Bi     = (const float*)d_in[3];
    const float* Cr     = (const float*)d_in[4];
    const float* Ci     = (const float*)d_in[5];
    const float* v_log  = (const float*)d_in[6];
    const float* th_log = (const float*)d_in[7];
    float* out = (float*)d_out;

    const size_t MB = 1024 * 1024;
    if (ws_size < 54 * MB) return;
    const bool big = (ws_size >= 86 * MB);   // non-aliased hp_bf -> 4-dispatch path

    char* ws = (char*)d_ws;
    u16*   Ccat     = (u16*)ws;                   // [1024,4096] bf16
    u16*   Bcat     = (u16*)(ws + 8 * MB);        // [1024,4096] bf16 = [BrT|BiT]
    float* partials = (float*)(ws + 16 * MB);     // [8][1024][1024] f32
    u16*   x_bf     = (u16*)ws;                   // [8192,1024] bf16 (aliases Ccat/Bcat, dead)
    u16*   Wmain    = (u16*)(ws + 48 * MB);       // [1024,1024] bf16
    u16*   Cwbf     = (u16*)(ws + 50 * MB);       // [1024,2048] bf16
    // hp_bf: big path = fresh region above 54MB (partials stay live during casts);
    //        small path = round-0 aliasing over partials (reduce must finish first).
    u16*   hp_bf    = big ? (u16*)(ws + 54 * MB) : (u16*)(ws + 16 * MB);

    // 1) prep: Ccat=[Cr|-Ci], Bcat=[Br^T|Bi^T], Cwbf=bf16(Cr*wr-Ci*wi)
    prep_kernel<<<10240, 256, 0, stream>>>(Cr, Ci, Br, Bi, v_log, th_log,
                                           Ccat, Bcat, Cwbf);
    // 2) partials = Ccat @ Bcat^T (split-K=8, 512 blocks, no tail)
    gemm_splitk_kernel<<<dim3(8, 8, 8), 256, 0, stream>>>(Ccat, Bcat, partials);
    // 3) Wmain = bf16(sum partials); x/h_prev -> bf16
    if (big) {
        reduce_cast_kernel<<<25600, 256, 0, stream>>>(partials, x, h_prev,
                                                      Wmain, x_bf, hp_bf);
    } else {
        reduce_only_kernel<<<1024, 256, 0, stream>>>(partials, Wmain);
        cast_both_kernel<<<24576, 256, 0, stream>>>(x, h_prev, x_bf);
    }
    // 4) out = [x_bf | hp_bf] @ [Wmain | Cwbf]^T  (256x128 tile, 3-deep pipeline)
    gemm_main_kernel<<<256, 512, 0, stream>>>(x_bf, hp_bf, Wmain, Cwbf, out);
}